// Round 19
// baseline (77.575 us; speedup 1.0000x reference)
//
#include <hip/hip_runtime.h>

#define B_ 2048
#define T_ 500
#define BT (B_ * T_)

// ---------------------------------------------------------------------------
// Masked Izhikevich Euler step — association order matches the reference
// exactly (DT=0.25, all a=0.02 -> DT*a = 0.005f). Invalid lanes hold state.
// ---------------------------------------------------------------------------
__device__ __forceinline__ float izh_m(float& v, float& u, float I,
                                       float b, float c, float d, bool valid) {
    float t  = 0.04f * v * v + 5.0f * v + 140.0f - u + I;
    float v_ = v + 0.25f * t;
    float u_ = u + 0.005f * (b * v - u);
    float z  = (v_ >= 30.0f) ? 1.0f : 0.0f;
    float vn = (v_ >= 30.0f) ? c : v_;
    float un = u_ + z * d;
    if (!valid) { z = 0.f; vn = v; un = u; }
    v = vn; u = un;
    return z;
}

// DPP row-shift-right by 1 within each 16-lane row; OOB lanes read 0.
__device__ __forceinline__ float dpp_shr1(float x) {
    return __int_as_float(__builtin_amdgcn_update_dpp(
        0, __float_as_int(x), 0x111, 0xf, 0xf, true));
}
// quad_perm [1,0,3,2] = lane^1 within quads
__device__ __forceinline__ float dpp_qx1(float x) {
    return __int_as_float(__builtin_amdgcn_update_dpp(
        0, __float_as_int(x), 0xB1, 0xf, 0xf, true));
}
// quad_perm [2,3,0,1] = lane^2 within quads
__device__ __forceinline__ float dpp_qx2(float x) {
    return __int_as_float(__builtin_amdgcn_update_dpp(
        0, __float_as_int(x), 0x4E, 0xf, 0xf, true));
}

// ---------------------------------------------------------------------------
// v12 MONOLITHIC BARRIER-FREE: 2048 blocks x 64 threads, one wave per block
// does load + in-lane reduce + scan + dump for ONE batch row. No s_barrier
// anywhere — all ordering is the wave's own in-order vmcnt/lgkmcnt queues.
// Differences vs the failed v7 monolith: no v_readlane in the scan operand
// path (S sums go through a tiny LDS buffer read back as BROADCAST
// ds_read_b128), and the reduce is in-lane + 2 quad-DPP (no shfl tree).
// Scanner: gap-3 systolic, all-distance-1 layout (v6/v11, unchanged).
// ---------------------------------------------------------------------------
__global__ __launch_bounds__(64, 2) void mono2_scan_kernel(
        const float* __restrict__ in, const float* __restrict__ w24,
        float* __restrict__ out) {
    __shared__ float S_lds[32];        // [2 bufs][16 t]
    __shared__ float ring[64 * 14];    // [64 slots][14 floats]

    const int lane = threadIdx.x;
    const int b    = blockIdx.x;       // ONE batch row per block

    // ---------------- scanner per-lane config (v11, unchanged) -------------
    const int c     = lane >> 4;       // 0 = active chain
    const int slot  = lane & 15;
    const int chl   = slot >> 3;       // 0 = channel 1, 1 = channel 2
    const int role8 = slot & 7;        // 0:L 1:E 2:I 3:idle 4:L' 5:E' 6:T 7:M

    const float a0   = chl ? w24[12] : w24[0];
    const float W1v  = chl ? w24[13] : w24[1];
    const float W4v  = chl ? w24[16] : w24[4];
    const float W5x  = chl ? w24[17] : w24[5];
    const float W6v  = chl ? w24[18] : w24[6];
    const float W8v  = chl ? w24[20] : w24[8];
    const float W11v = chl ? w24[23] : w24[11];
    const float W2 = w24[2], W3 = w24[3], W9 = w24[9], W10 = w24[10];

    float pb, pcc, pd, v, u, wA, wB, wC, wD;
    float fL = 0.f, fE = 0.f, fITM = 0.f;
    int offs;
    if (role8 == 0 || role8 == 4) {        // L / L': w2*(zp*w1) + w3*z2(self)
        pb=0.20f; pcc=-65.f; pd=6.f;   v=-70.f; u=-14.f;
        wA=W2;  wB=W1v;  wC=0.f; wD=W3;  offs=0; fL=1.f;
    } else if (role8 == 1 || role8 == 5) { // E / E': zp*w4 + z2*w5 (z2 <- slot-1)
        pb=0.25f; pcc=-55.f; pd=0.05f; v=-64.f; u=-16.f;
        wA=1.f; wB=W4v;  wC=W5x; wD=0.f; offs=3; fE=1.f;
    } else if (role8 == 2) {               // I: z3*w6 (z3 <- slot-1 = E)
        pb=0.25f; pcc=-65.f; pd=6.f;   v=-64.f; u=-16.f;
        wA=1.f; wB=W6v;  wC=0.f; wD=0.f; offs=6; fITM=1.f;
    } else if (role8 == 6) {               // T: w9*(z3*w8)+w10*z5(self) (z3 <- slot-1 = E')
        pb=0.20f; pcc=-50.f; pd=2.f;   v=-70.f; u=-14.f;
        wA=W9;  wB=W8v;  wC=0.f; wD=W10; offs=6; fITM=1.f;
    } else if (role8 == 7) {               // M: z5*w11 (z5 <- slot-1 = T)
        pb=0.25f; pcc=-65.f; pd=6.f;   v=-64.f; u=-16.f;
        wA=1.f; wB=W11v; wC=0.f; wD=0.f; offs=9; fITM=1.f;
    } else {                               // slot 3: idle
        pb=0.25f; pcc=-65.f; pd=6.f;   v=-64.f; u=-16.f;
        wA=0.f; wB=0.f;  wC=0.f; wD=0.f; offs=9;
    }
    // ring pairs: p0=(z2,vL)@s0 p1=(z3,vE)@s1 p2=(z4,vI)@s2 p3=(z5,vT)@s6
    //             p4=(z6,vM)@s7 ; p5=(z62,vM2)@s15. Only chain 0 writes.
    const bool wr = (c == 0) &&
        ((chl == 0 && (role8 <= 2 || role8 == 6 || role8 == 7)) ||
         (chl == 1 && role8 == 7));
    int p = 0;
    if (role8 == 1) p = 1;
    else if (role8 == 2) p = 2;
    else if (role8 == 6) p = 3;
    else if (role8 == 7) p = chl ? 5 : 4;
    const int ringoff = 2 * p;

    float z_last = 0.f, in_p1 = 0.f, in_p2 = 0.f;
    float zp1 = 0.f, zp2 = 0.f, zp3 = 0.f;

    // load mapping: atom t = lane>>2 (16 atoms), chunk = lane&3 (16 floats)
    const int latom = lane >> 2, lchunk = lane & 3;
    const float* inb = in + (size_t)b * T_ * 64;
    float4 A[4], Bv[4];                // ping-pong, static indexing

#define ISSUE(KK, BUF) {                                                       \
    const int t0i = 16 * (KK);                                                 \
    const int ttc = (t0i + latom <= 499) ? latom : 0;                          \
    const float* ap = inb + (size_t)(t0i + ttc) * 64 + lchunk * 16;            \
    _Pragma("unroll")                                                          \
    for (int ck = 0; ck < 4; ++ck) BUF[ck] = *(const float4*)(ap + ck * 4);    \
}

// Bit-exact tree (validated in v11): q_c=(x+y)+(z+w); a0=q0+q1, a1=q2+q3,
// bs=a0+a1; cs=bs+(lane^1); ss=cs+(lane^2). One ds_write_b32 per atom.
#define REDUCE(KK, BUF) {                                                      \
    float4 t_;                                                                 \
    t_ = BUF[0]; float q0_ = (t_.x + t_.y) + (t_.z + t_.w);                    \
    t_ = BUF[1]; float q1_ = (t_.x + t_.y) + (t_.z + t_.w);                    \
    t_ = BUF[2]; float q2_ = (t_.x + t_.y) + (t_.z + t_.w);                    \
    t_ = BUF[3]; float q3_ = (t_.x + t_.y) + (t_.z + t_.w);                    \
    float a0_ = q0_ + q1_, a1_ = q2_ + q3_;                                    \
    float bs_ = a0_ + a1_;                                                     \
    float cs_ = bs_ + dpp_qx1(bs_);                                            \
    float ss_ = cs_ + dpp_qx2(cs_);                                            \
    if (lchunk == 0)                                                           \
        S_lds[((KK) & 1) * 16 + latom] =                                       \
            (16 * (KK) + latom <= 499) ? ss_ : 0.f;                            \
}

#define SYS_ITER(SV, VEXPR, I_) {                                              \
    float in0 = in_p2;                                                         \
    in_p2 = in_p1;                                                             \
    in_p1 = dpp_shr1(z_last);                                                  \
    float zpc = (SV) * a0;                                                     \
    float X = (fL * zpc + fE * zp3) + fITM * in0;                              \
    float Isyn = wA * (X * wB) + wC * in0 + wD * z_last;                       \
    float znew = izh_m(v, u, Isyn, pb, pcc, pd, (VEXPR));                      \
    if (wr) *(float2*)(ringp + (I_) * 14) = make_float2(znew, v);              \
    zp3 = zp2; zp2 = zp1; zp1 = zpc;                                           \
    z_last = znew;                                                             \
}

#define GROUP16(VF)                                                            \
    SYS_ITER(g0.x, VF(0),  0)  SYS_ITER(g0.y, VF(1),  1)                       \
    SYS_ITER(g0.z, VF(2),  2)  SYS_ITER(g0.w, VF(3),  3)                       \
    SYS_ITER(g1.x, VF(4),  4)  SYS_ITER(g1.y, VF(5),  5)                       \
    SYS_ITER(g1.z, VF(6),  6)  SYS_ITER(g1.w, VF(7),  7)                       \
    SYS_ITER(g2.x, VF(8),  8)  SYS_ITER(g2.y, VF(9),  9)                       \
    SYS_ITER(g2.z, VF(10), 10) SYS_ITER(g2.w, VF(11), 11)                      \
    SYS_ITER(g3.x, VF(12), 12) SYS_ITER(g3.y, VF(13), 13)                      \
    SYS_ITER(g3.z, VF(14), 14) SYS_ITER(g3.w, VF(15), 15)

#define VF_PRO(i)  ((i) >= offs)
#define VF_ONE(i)  true
#define VF_EPI(i)  ((i) <= 3 + offs)

// DUMP(K): same wave, after SCANP(K+1). Reads j in [16K-9, 16K+15]; live
// write window extends to 16K+31 -> total span 41 <= 64 slots, race-free.
// In-order LDS + compiler lgkmcnt give RAW correctness with no fences.
#define DUMP(K) {                                                              \
    const int td = lane & 15;                                                  \
    const int t  = 16 * (K) - 9 + td;                                          \
    if (lane < 16 && 0 <= t && t <= 499) {                                     \
        float2 a2 = *(const float2*)&ring[((t)     & 63) * 14 + 0];            \
        float2 b2 = *(const float2*)&ring[((t + 3) & 63) * 14 + 2];            \
        float2 c1 = *(const float2*)&ring[((t + 6) & 63) * 14 + 4];            \
        float2 c2 = *(const float2*)&ring[((t + 6) & 63) * 14 + 6];            \
        float2 e1 = *(const float2*)&ring[((t + 9) & 63) * 14 + 8];            \
        float2 e2 = *(const float2*)&ring[((t + 9) & 63) * 14 + 10];           \
        const size_t g = (size_t)b * T_ + t;                                   \
        out[g]          = e1.x;   /* o_spikes  = z6  */                        \
        out[BT + g]     = e1.y;   /* v         = vM  */                        \
        out[2 * BT + g] = e2.x;   /* o_spikes2 = z62 */                        \
        out[3 * BT + g] = e2.y;   /* v2        = vM2 */                        \
        ((float4*)out)[BT + g]     = make_float4(a2.x, b2.x, c1.x, c2.x);      \
        ((float4*)out)[2 * BT + g] = make_float4(a2.y, b2.y, c1.y, c2.y);      \
    }                                                                          \
}

// Scanner period K: S consumed via broadcast ds_read_b128 (all lanes read
// the same address -> LDS broadcast, conflict-free, no readlane).
#define SCANP(K, VFSEL) {                                                      \
    const float4* sp = (const float4*)(S_lds + ((K) & 1) * 16);                \
    float4 g0 = sp[0], g1 = sp[1], g2 = sp[2], g3 = sp[3];                     \
    float* ringp = ring + ((K) & 3) * 224 + ringoff;                           \
    GROUP16(VFSEL)                                                             \
}

    // ---------------- prologue ----------------
    ISSUE(0, A)
    REDUCE(0, A)               // one-time vmcnt wait on first loads
    ISSUE(1, Bv)

    // ---------------- main: periods 0..31 (unrolled x2 for reg ping-pong) ---
    for (int k = 0; k < 32; k += 2) {
        // even period k
        if (k + 2 < 32) { ISSUE(k + 2, A) }
        if (k + 1 < 32) { REDUCE(k + 1, Bv) }   // -> S[(k+1)&1]
        if (k == 0) { SCANP(k, VF_PRO) } else { SCANP(k, VF_ONE) }
        if (k >= 1) { DUMP(k - 1) }
        // odd period k+1
        if (k + 3 < 32) { ISSUE(k + 3, Bv) }
        if (k + 2 < 32) { REDUCE(k + 2, A) }    // -> S[k&1] (after SCANP(k) read it)
        if (k + 1 == 31) { SCANP(k + 1, VF_EPI) } else { SCANP(k + 1, VF_ONE) }
        DUMP(k)
    }
    // final dump (period 31's tail)
    DUMP(31)

#undef ISSUE
#undef REDUCE
#undef SYS_ITER
#undef GROUP16
#undef VF_PRO
#undef VF_ONE
#undef VF_EPI
#undef DUMP
#undef SCANP
}

extern "C" void kernel_launch(void* const* d_in, const int* in_sizes, int n_in,
                              void* d_out, int out_size, void* d_ws, size_t ws_size,
                              hipStream_t stream) {
    const float* in = (const float*)d_in[0];
    const float* w  = (const float*)d_in[1];
    float* out = (float*)d_out;

    // 2048 single-wave blocks (one batch row each); zero barriers.
    mono2_scan_kernel<<<B_, 64, 0, stream>>>(in, w, out);
}

// Round 20
// 68.644 us; speedup vs baseline: 1.1301x; 1.1301x over previous
//
#include <hip/hip_runtime.h>

#define B_ 2048
#define T_ 500
#define BT (B_ * T_)

// ---------------------------------------------------------------------------
// Masked Izhikevich Euler step — association order matches the reference
// exactly (DT=0.25, all a=0.02 -> DT*a = 0.005f). Invalid lanes hold state.
// ---------------------------------------------------------------------------
__device__ __forceinline__ float izh_m(float& v, float& u, float I,
                                       float b, float c, float d, bool valid) {
    float t  = 0.04f * v * v + 5.0f * v + 140.0f - u + I;
    float v_ = v + 0.25f * t;
    float u_ = u + 0.005f * (b * v - u);
    float z  = (v_ >= 30.0f) ? 1.0f : 0.0f;
    float vn = (v_ >= 30.0f) ? c : v_;
    float un = u_ + z * d;
    if (!valid) { z = 0.f; vn = v; un = u; }
    v = vn; u = un;
    return z;
}

// DPP row-shift-right by 1 within each 16-lane row; OOB lanes read 0.
__device__ __forceinline__ float dpp_shr1(float x) {
    return __int_as_float(__builtin_amdgcn_update_dpp(
        0, __float_as_int(x), 0x111, 0xf, 0xf, true));
}
// quad_perm [1,0,3,2] = lane^1 within quads
__device__ __forceinline__ float dpp_qx1(float x) {
    return __int_as_float(__builtin_amdgcn_update_dpp(
        0, __float_as_int(x), 0xB1, 0xf, 0xf, true));
}
// quad_perm [2,3,0,1] = lane^2 within quads
__device__ __forceinline__ float dpp_qx2(float x) {
    return __int_as_float(__builtin_amdgcn_update_dpp(
        0, __float_as_int(x), 0x4E, 0xf, 0xf, true));
}

// LDS-only workgroup barrier (lgkmcnt, never vmcnt).
#define BAR() do {                                                             \
    asm volatile("s_waitcnt lgkmcnt(0)" ::: "memory");                         \
    __builtin_amdgcn_s_barrier();                                              \
    __builtin_amdgcn_sched_barrier(0);                                         \
} while (0)

// ---------------------------------------------------------------------------
// v11 (champion, 70.07 us): ONE ROW PER BLOCK, 2048 blocks x 128 threads
// (scanner + loader wave). 8 blocks/CU -> 16 waves/CU -> 4 waves/SIMD
// (2 scanners + 2 loaders): the second scanner wave on each SIMD fills the
// first's dependency-chain bubbles. Scanner: gap-3 systolic, all-distance-1
// slot layout; only chain 0 (lanes 0-15) stores. Loader: 4 KB/period,
// in-lane + quad-DPP tree (bit-exact), 2-period register ping-pong, DUMP one
// period behind (64-deep ring, race-free).
// ---------------------------------------------------------------------------
__global__ __launch_bounds__(128, 4) void fused_scan11_kernel(
        const float* __restrict__ in, const float* __restrict__ w24,
        float* __restrict__ out) {
    __shared__ float S_lds[128];       // [2 bufs][64] (only [0..15] written)
    __shared__ float ring[64 * 14];    // [64 slots][14 floats]

    const int tid   = threadIdx.x;
    const int wid   = tid >> 6;        // 0 = scanner, 1 = loader
    const int lane  = tid & 63;
    const int b     = blockIdx.x;      // ONE batch row per block

    // ---------------- scanner per-lane config ----------------
    const int c     = lane >> 4;       // 0 = active chain
    const int slot  = lane & 15;
    const int chl   = slot >> 3;       // 0 = channel 1, 1 = channel 2
    const int role8 = slot & 7;        // 0:L 1:E 2:I 3:idle 4:L' 5:E' 6:T 7:M

    const float a0   = chl ? w24[12] : w24[0];
    const float W1v  = chl ? w24[13] : w24[1];
    const float W4v  = chl ? w24[16] : w24[4];
    const float W5x  = chl ? w24[17] : w24[5];
    const float W6v  = chl ? w24[18] : w24[6];
    const float W8v  = chl ? w24[20] : w24[8];
    const float W11v = chl ? w24[23] : w24[11];
    const float W2 = w24[2], W3 = w24[3], W9 = w24[9], W10 = w24[10];

    float pb, pcc, pd, v, u, wA, wB, wC, wD;
    float fL = 0.f, fE = 0.f, fITM = 0.f;
    int offs;
    if (role8 == 0 || role8 == 4) {        // L / L': w2*(zp*w1) + w3*z2(self)
        pb=0.20f; pcc=-65.f; pd=6.f;   v=-70.f; u=-14.f;
        wA=W2;  wB=W1v;  wC=0.f; wD=W3;  offs=0; fL=1.f;
    } else if (role8 == 1 || role8 == 5) { // E / E': zp*w4 + z2*w5 (z2 <- slot-1)
        pb=0.25f; pcc=-55.f; pd=0.05f; v=-64.f; u=-16.f;
        wA=1.f; wB=W4v;  wC=W5x; wD=0.f; offs=3; fE=1.f;
    } else if (role8 == 2) {               // I: z3*w6 (z3 <- slot-1 = E)
        pb=0.25f; pcc=-65.f; pd=6.f;   v=-64.f; u=-16.f;
        wA=1.f; wB=W6v;  wC=0.f; wD=0.f; offs=6; fITM=1.f;
    } else if (role8 == 6) {               // T: w9*(z3*w8)+w10*z5(self) (z3 <- slot-1 = E')
        pb=0.20f; pcc=-50.f; pd=2.f;   v=-70.f; u=-14.f;
        wA=W9;  wB=W8v;  wC=0.f; wD=W10; offs=6; fITM=1.f;
    } else if (role8 == 7) {               // M: z5*w11 (z5 <- slot-1 = T)
        pb=0.25f; pcc=-65.f; pd=6.f;   v=-64.f; u=-16.f;
        wA=1.f; wB=W11v; wC=0.f; wD=0.f; offs=9; fITM=1.f;
    } else {                               // slot 3: idle
        pb=0.25f; pcc=-65.f; pd=6.f;   v=-64.f; u=-16.f;
        wA=0.f; wB=0.f;  wC=0.f; wD=0.f; offs=9;
    }
    // ring pairs: p0=(z2,vL)@s0 p1=(z3,vE)@s1 p2=(z4,vI)@s2 p3=(z5,vT)@s6
    //             p4=(z6,vM)@s7 ; p5=(z62,vM2)@s15. Only chain 0 writes.
    const bool wr = (c == 0) &&
        ((chl == 0 && (role8 <= 2 || role8 == 6 || role8 == 7)) ||
         (chl == 1 && role8 == 7));
    int p = 0;
    if (role8 == 1) p = 1;
    else if (role8 == 2) p = 2;
    else if (role8 == 6) p = 3;
    else if (role8 == 7) p = chl ? 5 : 4;
    const int ringoff = 2 * p;

    float z_last = 0.f, in_p1 = 0.f, in_p2 = 0.f;
    float zp1 = 0.f, zp2 = 0.f, zp3 = 0.f;

    // loader mapping: atom t = lane>>2 (16 atoms), chunk = lane&3 (4x16 floats)
    const int latom = lane >> 2, lchunk = lane & 3;
    const float* inb = in + (size_t)b * T_ * 64;
    float4 A[4], Bv[4];                // ping-pong, static indexing

#define ISSUE(KK, BUF) {                                                       \
    const int t0i = 16 * (KK);                                                 \
    const int ttc = (t0i + latom <= 499) ? latom : 0;                          \
    const float* ap = inb + (size_t)(t0i + ttc) * 64 + lchunk * 16;            \
    _Pragma("unroll")                                                          \
    for (int ck = 0; ck < 4; ++ck) BUF[ck] = *(const float4*)(ap + ck * 4);    \
}

// Bit-exact tree: q_c=(x+y)+(z+w); lane holds chunks 4j..4j+3:
// a0=q0+q1, a1=q2+q3, bsum=a0+a1 (level-2 node); c=bsum+(lane^1);
// s=c+(lane^2). Commuted adds only -> bitwise identical to validated tree.
#define REDUCE(KK, BUF) {                                                      \
    float4 t_;                                                                 \
    t_ = BUF[0]; float q0_ = (t_.x + t_.y) + (t_.z + t_.w);                    \
    t_ = BUF[1]; float q1_ = (t_.x + t_.y) + (t_.z + t_.w);                    \
    t_ = BUF[2]; float q2_ = (t_.x + t_.y) + (t_.z + t_.w);                    \
    t_ = BUF[3]; float q3_ = (t_.x + t_.y) + (t_.z + t_.w);                    \
    float a0_ = q0_ + q1_, a1_ = q2_ + q3_;                                    \
    float bs_ = a0_ + a1_;                                                     \
    float cs_ = bs_ + dpp_qx1(bs_);                                            \
    float ss_ = cs_ + dpp_qx2(cs_);                                            \
    if (lchunk == 0)                                                           \
        S_lds[((KK) & 1) * 64 + latom] =                                       \
            (16 * (KK) + latom <= 499) ? ss_ : 0.f;                            \
}

#define SYS_ITER(SV, VEXPR, I_) {                                              \
    float in0 = in_p2;                                                         \
    in_p2 = in_p1;                                                             \
    in_p1 = dpp_shr1(z_last);                                                  \
    float zpc = (SV) * a0;                                                     \
    float X = (fL * zpc + fE * zp3) + fITM * in0;                              \
    float Isyn = wA * (X * wB) + wC * in0 + wD * z_last;                       \
    float znew = izh_m(v, u, Isyn, pb, pcc, pd, (VEXPR));                      \
    if (wr) *(float2*)(ringp + (I_) * 14) = make_float2(znew, v);              \
    zp3 = zp2; zp2 = zp1; zp1 = zpc;                                           \
    z_last = znew;                                                             \
}

#define GROUP16(VF)                                                            \
    SYS_ITER(g0.x, VF(0),  0)  SYS_ITER(g0.y, VF(1),  1)                       \
    SYS_ITER(g0.z, VF(2),  2)  SYS_ITER(g0.w, VF(3),  3)                       \
    SYS_ITER(g1.x, VF(4),  4)  SYS_ITER(g1.y, VF(5),  5)                       \
    SYS_ITER(g1.z, VF(6),  6)  SYS_ITER(g1.w, VF(7),  7)                       \
    SYS_ITER(g2.x, VF(8),  8)  SYS_ITER(g2.y, VF(9),  9)                       \
    SYS_ITER(g2.z, VF(10), 10) SYS_ITER(g2.w, VF(11), 11)                      \
    SYS_ITER(g3.x, VF(12), 12) SYS_ITER(g3.y, VF(13), 13)                      \
    SYS_ITER(g3.z, VF(14), 14) SYS_ITER(g3.w, VF(15), 15)

#define VF_PRO(i)  ((i) >= offs)
#define VF_ONE(i)  true
#define VF_EPI(i)  ((i) <= 3 + offs)

// DUMP(K): loader, one period behind. Lanes 0-15 only (one row). Ring reads
// stride 14 floats (56B) -> 16 distinct banks, conflict-free.
#define DUMP(K) {                                                              \
    const int td = lane & 15;                                                  \
    const int t  = 16 * (K) - 9 + td;                                          \
    if (lane < 16 && 0 <= t && t <= 499) {                                     \
        float2 a2 = *(const float2*)&ring[((t)     & 63) * 14 + 0];            \
        float2 b2 = *(const float2*)&ring[((t + 3) & 63) * 14 + 2];            \
        float2 c1 = *(const float2*)&ring[((t + 6) & 63) * 14 + 4];            \
        float2 c2 = *(const float2*)&ring[((t + 6) & 63) * 14 + 6];            \
        float2 e1 = *(const float2*)&ring[((t + 9) & 63) * 14 + 8];            \
        float2 e2 = *(const float2*)&ring[((t + 9) & 63) * 14 + 10];           \
        const size_t g = (size_t)b * T_ + t;                                   \
        out[g]          = e1.x;   /* o_spikes  = z6  */                        \
        out[BT + g]     = e1.y;   /* v         = vM  */                        \
        out[2 * BT + g] = e2.x;   /* o_spikes2 = z62 */                        \
        out[3 * BT + g] = e2.y;   /* v2        = vM2 */                        \
        ((float4*)out)[BT + g]     = make_float4(a2.x, b2.x, c1.x, c2.x);      \
        ((float4*)out)[2 * BT + g] = make_float4(a2.y, b2.y, c1.y, c2.y);      \
    }                                                                          \
}

// Scanner period K: ring slots (K&3)*16 .. +15.
#define SCANP(K, VFSEL) {                                                      \
    const float4* sp = (const float4*)(S_lds + ((K) & 1) * 64 + c * 16);       \
    float4 g0 = sp[0], g1 = sp[1], g2 = sp[2], g3 = sp[3];                     \
    float* ringp = ring + ((K) & 3) * 224 + ringoff;                           \
    GROUP16(VFSEL)                                                             \
}

    // ---------------- prologue ----------------
    if (wid == 1) {
        ISSUE(0, A)
        REDUCE(0, A)           // one-time vmcnt wait on first loads
        ISSUE(1, Bv)
    }
    BAR();                     // S_lds buf0 ready; ISSUE(1) stays in flight

    // ---------------- main: periods 0..31 (unrolled x2 for reg ping-pong) ---
    for (int k = 0; k < 32; k += 2) {
        if (wid == 0) {
            if (k == 0) { SCANP(k, VF_PRO) } else { SCANP(k, VF_ONE) }
        } else {
            if (k + 2 < 32) { ISSUE(k + 2, A) }
            if (k + 1 < 32) { REDUCE(k + 1, Bv) }
            if (k >= 1) { DUMP(k - 1) }
        }
        BAR();
        if (wid == 0) {
            if (k + 1 == 31) { SCANP(k + 1, VF_EPI) } else { SCANP(k + 1, VF_ONE) }
        } else {
            if (k + 3 < 32) { ISSUE(k + 3, Bv) }
            if (k + 2 < 32) { REDUCE(k + 2, A) }
            DUMP(k)
        }
        BAR();
    }
    // final dump (period 31's tail), after the last BAR
    if (wid == 1) { DUMP(31) }

#undef ISSUE
#undef REDUCE
#undef SYS_ITER
#undef GROUP16
#undef VF_PRO
#undef VF_ONE
#undef VF_EPI
#undef DUMP
#undef SCANP
}

extern "C" void kernel_launch(void* const* d_in, const int* in_sizes, int n_in,
                              void* d_out, int out_size, void* d_ws, size_t ws_size,
                              hipStream_t stream) {
    const float* in = (const float*)d_in[0];
    const float* w  = (const float*)d_in[1];
    float* out = (float*)d_out;

    // 2048 blocks x 128 threads (1 scanner + 1 loader wave), ONE row each.
    // 8 blocks/CU -> 2 scanner waves per SIMD -> dep-chain bubbles filled.
    fused_scan11_kernel<<<B_, 128, 0, stream>>>(in, w, out);
}